// Round 5
// baseline (274.069 us; speedup 1.0000x reference)
//
#include <hip/hip_runtime.h>

// ARCQuantLayer: out = q(x)·q(W)^T + (x-q(x))[:,idx]·arc^T, q(v)=round(v*8)/8.
// q() is EXACT in bf16 -> single fused bf16 GEMM, K = 4096 + 256(padded outliers).
// GEMM: 256x256 tile, BK=32, 4-deep LDS pipeline, counted vmcnt (T4), one barrier
// per K-tile, XOR-swizzled LDS via pre-swizzled global source (T2), setprio (T5),
// 2D XCD-chunked tile map (T1), and cross-region REGISTER double-buffering of
// fragments (reads of tile t+1 issued under tile t's MFMA clusters).

#define M_DIM 8192
#define N_DIM 4096
#define K_DIM 4096
#define KO_PAD 256
#define K_PAD (K_DIM + KO_PAD)  // 4352
#define NT (K_PAD / 32)         // 136 K-tiles for the 256^2 kernel

typedef __bf16 bf16x8 __attribute__((ext_vector_type(8)));
typedef float f32x4 __attribute__((ext_vector_type(4)));

__device__ __forceinline__ void async16(const void* g, void* l) {
  __builtin_amdgcn_global_load_lds(
      (__attribute__((address_space(1))) void*)g,
      (__attribute__((address_space(3))) void*)l, 16, 0, 0);
}

__device__ __forceinline__ float qf(float f) { return rintf(f * 8.0f) * 0.125f; }
__device__ __forceinline__ __bf16 qbf(float f) { return (__bf16)qf(f); }

// ---- prep A rows [m0, m0+mr): A[ml][0:4096]=q(x), A[ml][4096+j]=residual (j<no) else 0
__global__ __launch_bounds__(256) void prep_x_kernel(const float* __restrict__ x,
                                                     const int* __restrict__ idx,
                                                     __bf16* __restrict__ A, int no,
                                                     int m0) {
  int gid = blockIdx.x * 256 + threadIdx.x;
  int ml = gid / (K_PAD / 8);
  int kk = (gid - ml * (K_PAD / 8)) * 8;
  const float* xr = x + (size_t)(m0 + ml) * K_DIM;
  bf16x8 r;
  if (kk < K_DIM) {
    float4 v0 = *(const float4*)(xr + kk);
    float4 v1 = *(const float4*)(xr + kk + 4);
    r[0] = qbf(v0.x); r[1] = qbf(v0.y); r[2] = qbf(v0.z); r[3] = qbf(v0.w);
    r[4] = qbf(v1.x); r[5] = qbf(v1.y); r[6] = qbf(v1.z); r[7] = qbf(v1.w);
  } else {
    int j = kk - K_DIM;
#pragma unroll
    for (int u = 0; u < 8; ++u) {
      float v = 0.f;
      int jj = j + u;
      if (jj < no) {
        float xv = xr[idx[jj]];
        v = xv - qf(xv);
      }
      r[u] = (__bf16)v;
    }
  }
  *(bf16x8*)(A + (size_t)ml * K_PAD + kk) = r;
}

// ---- prep B rows: B[ol][0:4096]=q(W), B[ol][4096+j]=arc (j<no) else 0
__global__ __launch_bounds__(256) void prep_w_kernel(const float* __restrict__ w,
                                                     const float* __restrict__ arc,
                                                     __bf16* __restrict__ B, int no,
                                                     int n0) {
  int gid = blockIdx.x * 256 + threadIdx.x;
  int ol = gid / (K_PAD / 8);
  int kk = (gid - ol * (K_PAD / 8)) * 8;
  int o = n0 + ol;
  bf16x8 r;
  if (kk < K_DIM) {
    const float* wr = w + (size_t)o * K_DIM;
    float4 v0 = *(const float4*)(wr + kk);
    float4 v1 = *(const float4*)(wr + kk + 4);
    r[0] = qbf(v0.x); r[1] = qbf(v0.y); r[2] = qbf(v0.z); r[3] = qbf(v0.w);
    r[4] = qbf(v1.x); r[5] = qbf(v1.y); r[6] = qbf(v1.z); r[7] = qbf(v1.w);
  } else {
    int j = kk - K_DIM;
#pragma unroll
    for (int u = 0; u < 8; ++u) {
      float v = 0.f;
      int jj = j + u;
      if (jj < no) v = arc[(size_t)o * no + jj];
      r[u] = (__bf16)v;
    }
  }
  *(bf16x8*)(B + (size_t)ol * K_PAD + kk) = r;
}

// ---- fast GEMM: C = A (8192 x K_PAD) * B^T (4096 x K_PAD), fp32 out.
// 256x256 tile, BK=32, 512 threads (8 waves 2Mx4N), 4 LDS buffers.
// Steady state per region(t): stage(t+3); vmcnt(8) [publishes t+1 landed];
// barrier; {MFMA tile t  ||  ds_read tile t+1 frags into ping-pong registers}.
__global__ __launch_bounds__(512, 2) void gemm256_kernel(const __bf16* __restrict__ A,
                                                         const __bf16* __restrict__ B,
                                                         float* __restrict__ C) {
  __shared__ __align__(16) __bf16 lds[4 * 16384];  // 4 bufs x (A 8192 + B 8192) = 128 KB

  const int tid = threadIdx.x;
  const int lane = tid & 63;
  const int wid = tid >> 6;
  const int wm = (wid >> 2) * 128;  // wave M offset in tile
  const int wn = (wid & 3) * 64;    // wave N offset in tile

  // 2D XCD-chunked map (verified r4: FETCH 574->215 MB)
  const int x = blockIdx.x & 7;
  const int j = blockIdx.x >> 3;
  const int bm = (x & 3) * 8 + (j >> 5) * 4 + ((j >> 3) & 3);  // 0..31
  const int bn = (x >> 2) * 8 + (j & 7);                       // 0..15
  const int bmRow = bm << 8;
  const int bnRow = bn << 8;

  // staging: thread covers LDS rows (tid>>2)+{0,128}, lin-slot tid&3; source k-slot
  // pre-swizzled: ss = (tid&3) ^ ((row>>1)&3)
  const int r0 = tid >> 2;
  const int ss = (tid & 3) ^ ((tid >> 3) & 3);
  const __bf16* gA0 = A + (size_t)(bmRow + r0) * K_PAD + ss * 8;
  const __bf16* gA1 = gA0 + (size_t)128 * K_PAD;
  const __bf16* gB0 = B + (size_t)(bnRow + r0) * K_PAD + ss * 8;
  const __bf16* gB1 = gB0 + (size_t)128 * K_PAD;
  const int dA = tid * 8;
  const int dB = 8192 + tid * 8;

  // fragment reads: row = base + fr, k-slot lane>>4 -> lin-slot (lane>>4)^((fr>>1)&3)
  const int fr = lane & 15;
  const int s2 = (lane >> 4) ^ ((fr >> 1) & 3);
  const int laneRd = fr * 32 + s2 * 8;
  const int aRd = wm * 32 + laneRd;
  const int bRd = 8192 + wn * 32 + laneRd;

  f32x4 acc[8][4] = {};

  auto stage = [&](int tt) {
    const int bb = (tt & 3) * 16384;
    const int ke = tt * 32;
    async16(gA0 + ke, (void*)&lds[bb + dA]);
    async16(gA1 + ke, (void*)&lds[bb + dA + 4096]);
    async16(gB0 + ke, (void*)&lds[bb + dB]);
    async16(gB1 + ke, (void*)&lds[bb + dB + 4096]);
  };

  stage(0);
  stage(1);
  stage(2);

  bf16x8 aX[4], bX[4], aY[4], bY[4];

  // prologue: wait tile0 landed (12 outstanding -> vmcnt(8) retires stage(0)),
  // publish via barrier, preload tile0 a[0..3], b[0..3].
  asm volatile("s_waitcnt vmcnt(8)" ::: "memory");
  __builtin_amdgcn_s_barrier();
  asm volatile("" ::: "memory");
#pragma unroll
  for (int i = 0; i < 4; ++i) aX[i] = *(const bf16x8*)&lds[aRd + i * 512];
#pragma unroll
  for (int n = 0; n < 4; ++n) bX[n] = *(const bf16x8*)&lds[bRd + n * 512];

  // region(t): on entry aC/bC hold tile-t frags (rows 0..3 of wave tile + all b).
  // AHEAD: 8 -> vmcnt(8), 4 -> vmcnt(4), 0 -> vmcnt(0), -1 -> none.
  auto region = [&](int t, bool do_stage, int ahead, bool rd,
                    bf16x8 (&aC)[4], bf16x8 (&bC)[4],
                    bf16x8 (&aN)[4], bf16x8 (&bN)[4]) {
    if (do_stage) stage(t + 3);  // target buf[(t-1)&3]: its readers hold data in regs
    if (ahead == 8)      asm volatile("s_waitcnt vmcnt(8)" ::: "memory");
    else if (ahead == 4) asm volatile("s_waitcnt vmcnt(4)" ::: "memory");
    else if (ahead == 0) asm volatile("s_waitcnt vmcnt(0)" ::: "memory");
    __builtin_amdgcn_s_barrier();  // publishes: all waves' tile-(t+1) loads landed
    asm volatile("" ::: "memory");
    const int bb = (t & 3) * 16384;
    const int bb1 = ((t + 1) & 3) * 16384;
    bf16x8 aH[4];  // tile t rows 4..7 (consumed by clusters 4..7, ~80+ cyc away)
#pragma unroll
    for (int i = 0; i < 4; ++i)
      aH[i] = *(const bf16x8*)&lds[bb + aRd + (4 + i) * 512];
    if (rd) {
#pragma unroll
      for (int n = 0; n < 4; ++n)
        bN[n] = *(const bf16x8*)&lds[bb1 + bRd + n * 512];
    }
    __builtin_amdgcn_s_setprio(1);
#pragma unroll
    for (int m = 0; m < 4; ++m)
#pragma unroll
      for (int n = 0; n < 4; ++n)
        acc[m][n] = __builtin_amdgcn_mfma_f32_16x16x32_bf16(aC[m], bC[n],
                                                            acc[m][n], 0, 0, 0);
    __builtin_amdgcn_s_setprio(0);
    if (rd) {
#pragma unroll
      for (int i = 0; i < 4; ++i)
        aN[i] = *(const bf16x8*)&lds[bb1 + aRd + i * 512];
    }
    __builtin_amdgcn_s_setprio(1);
#pragma unroll
    for (int m = 0; m < 4; ++m)
#pragma unroll
      for (int n = 0; n < 4; ++n)
        acc[4 + m][n] = __builtin_amdgcn_mfma_f32_16x16x32_bf16(aH[m], bC[n],
                                                                acc[4 + m][n], 0, 0, 0);
    __builtin_amdgcn_s_setprio(0);
    asm volatile("" ::: "memory");
  };

  // main: regions 0..131 (all stage, vmcnt(8)); ping-pong X->Y->X...
  for (int t = 0; t < NT - 4; t += 2) {
    region(t, true, 8, true, aX, bX, aY, bY);
    region(t + 1, true, 8, true, aY, bY, aX, bX);
  }
  region(NT - 4, true, 8, true, aX, bX, aY, bY);   // t=132: stage(135)
  region(NT - 3, false, 4, true, aY, bY, aX, bX);  // t=133: {134,135} out -> vmcnt(4)
  region(NT - 2, false, 0, true, aX, bX, aY, bY);  // t=134: {135} out -> vmcnt(0)
  region(NT - 1, false, -1, false, aY, bY, aX, bX);  // t=135: all landed

  // C/D layout: col=lane&15, row=(lane>>4)*4+j [m89/m91]
  const int cr = (lane >> 4) * 4;
  const int cc = lane & 15;
#pragma unroll
  for (int m = 0; m < 8; ++m) {
#pragma unroll
    for (int n = 0; n < 4; ++n) {
      float* cp = C + (size_t)(bmRow + wm + m * 16 + cr) * N_DIM +
                  (bnRow + wn + n * 16 + cc);
#pragma unroll
      for (int jj = 0; jj < 4; ++jj) cp[(size_t)jj * N_DIM] = acc[m][n][jj];
    }
  }
}

// ---- fallback chunked GEMM (m97 structure, verified round 2) ----
__global__ __launch_bounds__(256) void gemm_bt_kernel(const __bf16* __restrict__ A,
                                                      const __bf16* __restrict__ B,
                                                      float* __restrict__ C,
                                                      int m0, int n0, int mtiles) {
  __shared__ __align__(16) __bf16 sA[128 * 64];
  __shared__ __align__(16) __bf16 sB[128 * 64];

  const int bid = blockIdx.x;
  const int bm = bid % mtiles;
  const int bn = bid / mtiles;

  const int t = threadIdx.x;
  const int lane = t & 63;
  const int w = t >> 6;
  const int wm = (w >> 1) * 64;
  const int wn = (w & 1) * 64;

  f32x4 acc[4][4] = {};

  const __bf16* gA = A + (size_t)(bm * 128 + (t >> 3)) * K_PAD + (t & 7) * 8;
  const __bf16* gB = B + (size_t)(bn * 128 + (t >> 3)) * K_PAD + (t & 7) * 8;
  char* lA = (char*)sA + t * 16;
  char* lB = (char*)sB + t * 16;

  const int fr = lane & 15;
  const int fo = (lane >> 4) * 8;

  for (int kt = 0; kt < K_PAD / 64; ++kt) {
    const int k0 = kt * 64;
#pragma unroll
    for (int i = 0; i < 4; ++i) {
      async16(gA + k0 + (size_t)i * 32 * K_PAD, lA + i * 4096);
      async16(gB + k0 + (size_t)i * 32 * K_PAD, lB + i * 4096);
    }
    __syncthreads();
#pragma unroll
    for (int kk = 0; kk < 2; ++kk) {
      bf16x8 aF[4], bF[4];
#pragma unroll
      for (int mt = 0; mt < 4; ++mt)
        aF[mt] = *(const bf16x8*)&sA[(wm + mt * 16 + fr) * 64 + kk * 32 + fo];
#pragma unroll
      for (int nt = 0; nt < 4; ++nt)
        bF[nt] = *(const bf16x8*)&sB[(wn + nt * 16 + fr) * 64 + kk * 32 + fo];
#pragma unroll
      for (int mt = 0; mt < 4; ++mt)
#pragma unroll
        for (int nt = 0; nt < 4; ++nt)
          acc[mt][nt] = __builtin_amdgcn_mfma_f32_16x16x32_bf16(
              aF[mt], bF[nt], acc[mt][nt], 0, 0, 0);
    }
    __syncthreads();
  }

  const int cr = (lane >> 4) * 4;
  const int cc = lane & 15;
#pragma unroll
  for (int mt = 0; mt < 4; ++mt) {
#pragma unroll
    for (int nt = 0; nt < 4; ++nt) {
      float* cp = C + (size_t)(m0 + bm * 128 + wm + mt * 16 + cr) * N_DIM +
                  (n0 + bn * 128 + wn + nt * 16 + cc);
#pragma unroll
      for (int j = 0; j < 4; ++j) cp[(size_t)j * N_DIM] = acc[mt][nt][j];
    }
  }
}

// ---- safety net for tiny ws
__global__ __launch_bounds__(256) void naive_kernel(const float* __restrict__ x,
                                                    const float* __restrict__ w,
                                                    const float* __restrict__ arc,
                                                    const int* __restrict__ idx,
                                                    float* __restrict__ out, int no) {
  size_t gid = (size_t)blockIdx.x * 256 + threadIdx.x;
  if (gid >= (size_t)M_DIM * N_DIM) return;
  int m = (int)(gid / N_DIM), o = (int)(gid % N_DIM);
  const float* xr = x + (size_t)m * K_DIM;
  const float* wr = w + (size_t)o * K_DIM;
  float acc = 0.f;
  for (int k = 0; k < K_DIM; ++k) acc += qf(xr[k]) * qf(wr[k]);
  for (int j = 0; j < no; ++j) {
    float xv = xr[idx[j]];
    acc += (xv - qf(xv)) * arc[(size_t)o * no + j];
  }
  out[gid] = acc;
}

extern "C" void kernel_launch(void* const* d_in, const int* in_sizes, int n_in,
                              void* d_out, int out_size, void* d_ws, size_t ws_size,
                              hipStream_t stream) {
  const float* x = (const float*)d_in[0];     // (4,2048,4096)
  const float* wgt = (const float*)d_in[1];   // (4096,4096)
  const float* arc = (const float*)d_in[2];   // (4096,204)
  const int* idx = (const int*)d_in[3];       // (204,)
  float* out = (float*)d_out;                 // (4,2048,4096) fp32
  const int no = in_sizes[3];                 // 204

  const size_t rowb = (size_t)K_PAD * sizeof(__bf16);  // 8704 B per staged row
  const size_t rows_avail = ws_size / rowb;

  if (rows_avail >= (size_t)(N_DIM + M_DIM)) {
    // fast path: full A+B staged, single 256^2 pipelined GEMM
    __bf16* B = (__bf16*)d_ws;
    __bf16* A = B + (size_t)N_DIM * K_PAD;
    prep_w_kernel<<<N_DIM * (K_PAD / 8) / 256, 256, 0, stream>>>(wgt, arc, B, no, 0);
    prep_x_kernel<<<M_DIM * (K_PAD / 8) / 256, 256, 0, stream>>>(x, idx, A, no, 0);
    gemm256_kernel<<<(M_DIM / 256) * (N_DIM / 256), 512, 0, stream>>>(A, B, out);
    return;
  }

  // chunked fallback (multiples of 128 rows)
  size_t nr_c, mr_c;
  if (rows_avail >= (size_t)(N_DIM + 128)) {
    nr_c = N_DIM;
    mr_c = ((rows_avail - N_DIM) / 128) * 128;
    if (mr_c > M_DIM) mr_c = M_DIM;
  } else {
    nr_c = (rows_avail / 2 / 128) * 128;
    if (nr_c > N_DIM) nr_c = N_DIM;
    mr_c = nr_c ? (((rows_avail - nr_c) / 128) * 128) : 0;
    if (mr_c > M_DIM) mr_c = M_DIM;
  }

  if (nr_c == 0 || mr_c == 0) {
    size_t total = (size_t)M_DIM * N_DIM;
    naive_kernel<<<(int)((total + 255) / 256), 256, 0, stream>>>(x, wgt, arc, idx, out, no);
    return;
  }

  __bf16* B = (__bf16*)d_ws;
  __bf16* A = B + nr_c * (size_t)K_PAD;

  for (int n0 = 0; n0 < N_DIM; n0 += (int)nr_c) {
    const int nr = (int)((N_DIM - n0 < (int)nr_c) ? (N_DIM - n0) : (int)nr_c);
    prep_w_kernel<<<nr * (K_PAD / 8) / 256, 256, 0, stream>>>(wgt, arc, B, no, n0);
    for (int m0 = 0; m0 < M_DIM; m0 += (int)mr_c) {
      const int mr = (int)((M_DIM - m0 < (int)mr_c) ? (M_DIM - m0) : (int)mr_c);
      prep_x_kernel<<<mr * (K_PAD / 8) / 256, 256, 0, stream>>>(x, idx, A, no, m0);
      const int mtiles = mr / 128, ntiles = nr / 128;
      gemm_bt_kernel<<<mtiles * ntiles, 256, 0, stream>>>(A, B, out, m0, n0, mtiles);
    }
  }
}

// Round 6
// 270.696 us; speedup vs baseline: 1.0125x; 1.0125x over previous
//
#include <hip/hip_runtime.h>

// ARCQuantLayer: out = q(x)·q(W)^T + (x-q(x))[:,idx]·arc^T, q(v)=round(v*8)/8.
// q() is EXACT in bf16 -> single fused bf16 GEMM, K = 4096 + 256(padded outliers).
// GEMM: 256x256 tile, BK=32, 4-deep LDS pipeline, counted vmcnt (T4), m201-style
// PHASE-SPLIT body (2 phases/K-tile, 2 barriers each, 16-MFMA quadrant clusters)
// so MFMA drain overlaps the other waves' LDS read-bursts. Swizzle (T2), XCD map
// (T1), setprio (T5) unchanged from round 4/5 (verified: 0 bank conflicts).

#define M_DIM 8192
#define N_DIM 4096
#define K_DIM 4096
#define KO_PAD 256
#define K_PAD (K_DIM + KO_PAD)  // 4352
#define NT (K_PAD / 32)         // 136 K-tiles for the 256^2 kernel

typedef __bf16 bf16x8 __attribute__((ext_vector_type(8)));
typedef float f32x4 __attribute__((ext_vector_type(4)));

__device__ __forceinline__ void async16(const void* g, void* l) {
  __builtin_amdgcn_global_load_lds(
      (__attribute__((address_space(1))) void*)g,
      (__attribute__((address_space(3))) void*)l, 16, 0, 0);
}

__device__ __forceinline__ float qf(float f) { return rintf(f * 8.0f) * 0.125f; }
__device__ __forceinline__ __bf16 qbf(float f) { return (__bf16)qf(f); }

// ---- prep A rows [m0, m0+mr): A[ml][0:4096]=q(x), A[ml][4096+j]=residual (j<no) else 0
__global__ __launch_bounds__(256) void prep_x_kernel(const float* __restrict__ x,
                                                     const int* __restrict__ idx,
                                                     __bf16* __restrict__ A, int no,
                                                     int m0) {
  int gid = blockIdx.x * 256 + threadIdx.x;
  int ml = gid / (K_PAD / 8);
  int kk = (gid - ml * (K_PAD / 8)) * 8;
  const float* xr = x + (size_t)(m0 + ml) * K_DIM;
  bf16x8 r;
  if (kk < K_DIM) {
    float4 v0 = *(const float4*)(xr + kk);
    float4 v1 = *(const float4*)(xr + kk + 4);
    r[0] = qbf(v0.x); r[1] = qbf(v0.y); r[2] = qbf(v0.z); r[3] = qbf(v0.w);
    r[4] = qbf(v1.x); r[5] = qbf(v1.y); r[6] = qbf(v1.z); r[7] = qbf(v1.w);
  } else {
    int j = kk - K_DIM;
#pragma unroll
    for (int u = 0; u < 8; ++u) {
      float v = 0.f;
      int jj = j + u;
      if (jj < no) {
        float xv = xr[idx[jj]];
        v = xv - qf(xv);
      }
      r[u] = (__bf16)v;
    }
  }
  *(bf16x8*)(A + (size_t)ml * K_PAD + kk) = r;
}

// ---- prep B rows: B[ol][0:4096]=q(W), B[ol][4096+j]=arc (j<no) else 0
__global__ __launch_bounds__(256) void prep_w_kernel(const float* __restrict__ w,
                                                     const float* __restrict__ arc,
                                                     __bf16* __restrict__ B, int no,
                                                     int n0) {
  int gid = blockIdx.x * 256 + threadIdx.x;
  int ol = gid / (K_PAD / 8);
  int kk = (gid - ol * (K_PAD / 8)) * 8;
  int o = n0 + ol;
  bf16x8 r;
  if (kk < K_DIM) {
    const float* wr = w + (size_t)o * K_DIM;
    float4 v0 = *(const float4*)(wr + kk);
    float4 v1 = *(const float4*)(wr + kk + 4);
    r[0] = qbf(v0.x); r[1] = qbf(v0.y); r[2] = qbf(v0.z); r[3] = qbf(v0.w);
    r[4] = qbf(v1.x); r[5] = qbf(v1.y); r[6] = qbf(v1.z); r[7] = qbf(v1.w);
  } else {
    int j = kk - K_DIM;
#pragma unroll
    for (int u = 0; u < 8; ++u) {
      float v = 0.f;
      int jj = j + u;
      if (jj < no) v = arc[(size_t)o * no + jj];
      r[u] = (__bf16)v;
    }
  }
  *(bf16x8*)(B + (size_t)ol * K_PAD + kk) = r;
}

// ---- fast GEMM: C = A (8192 x K_PAD) * B^T (4096 x K_PAD), fp32 out.
// 256x256 tile, BK=32, 512 threads (8 waves 2Mx4N), 4 LDS buffers.
// Per K-tile t, two phases:
//  P-A: read aF0-3,bF0-3; stageA(t+3); BAR; lgkm0; 16 MFMA acc[0..3]
//  P-B: read aH4-7;       stageB(t+3); vmcnt(8); BAR; lgkm0; 16 MFMA acc[4..7]
// BAR(P-B of t) publishes tile t+1 landed (vmcnt(8) retires stage(t+1)).
__global__ __launch_bounds__(512, 2) void gemm256_kernel(const __bf16* __restrict__ A,
                                                         const __bf16* __restrict__ B,
                                                         float* __restrict__ C) {
  __shared__ __align__(16) __bf16 lds[4 * 16384];  // 4 bufs x (A 8192 + B 8192) = 128 KB

  const int tid = threadIdx.x;
  const int lane = tid & 63;
  const int wid = tid >> 6;
  const int wm = (wid >> 2) * 128;  // wave M offset in tile
  const int wn = (wid & 3) * 64;    // wave N offset in tile

  // 2D XCD-chunked map (verified r4: FETCH 574->215 MB)
  const int x = blockIdx.x & 7;
  const int j = blockIdx.x >> 3;
  const int bm = (x & 3) * 8 + (j >> 5) * 4 + ((j >> 3) & 3);  // 0..31
  const int bn = (x >> 2) * 8 + (j & 7);                       // 0..15
  const int bmRow = bm << 8;
  const int bnRow = bn << 8;

  // staging: thread covers LDS rows (tid>>2)+{0,128}, lin-slot tid&3; source k-slot
  // pre-swizzled: ss = (tid&3) ^ ((row>>1)&3)
  const int r0 = tid >> 2;
  const int ss = (tid & 3) ^ ((tid >> 3) & 3);
  const __bf16* gA0 = A + (size_t)(bmRow + r0) * K_PAD + ss * 8;
  const __bf16* gA1 = gA0 + (size_t)128 * K_PAD;
  const __bf16* gB0 = B + (size_t)(bnRow + r0) * K_PAD + ss * 8;
  const __bf16* gB1 = gB0 + (size_t)128 * K_PAD;
  const int dA = tid * 8;
  const int dB = 8192 + tid * 8;

  // fragment reads: row = base + fr, k-slot lane>>4 -> lin-slot (lane>>4)^((fr>>1)&3)
  const int fr = lane & 15;
  const int s2 = (lane >> 4) ^ ((fr >> 1) & 3);
  const int laneRd = fr * 32 + s2 * 8;
  const int aRd = wm * 32 + laneRd;
  const int bRd = 8192 + wn * 32 + laneRd;

  f32x4 acc[8][4] = {};

  auto stageA = [&](int tt) {
    const int bb = (tt & 3) * 16384;
    const int ke = tt * 32;
    async16(gA0 + ke, (void*)&lds[bb + dA]);
    async16(gA1 + ke, (void*)&lds[bb + dA + 4096]);
  };
  auto stageB = [&](int tt) {
    const int bb = (tt & 3) * 16384;
    const int ke = tt * 32;
    async16(gB0 + ke, (void*)&lds[bb + dB]);
    async16(gB1 + ke, (void*)&lds[bb + dB + 4096]);
  };

  stageA(0); stageB(0);
  stageA(1); stageB(1);
  stageA(2); stageB(2);

  // prologue: 12 loads out -> vmcnt(8) retires stage(0); BAR publishes tile 0.
  asm volatile("s_waitcnt vmcnt(8)" ::: "memory");
  __builtin_amdgcn_sched_barrier(0);
  __builtin_amdgcn_s_barrier();

  // region(t): stg 1 -> stage t+3, vmcnt(8); stg 0 -> no stage, vm = tail count.
  auto region = [&](int t, bool do_stage, int vm) {
    const int bb = (t & 3) * 16384;
    // ---- phase A: quadrant m0-3 x n0-3
    bf16x8 aF[4], bF[4];
#pragma unroll
    for (int i = 0; i < 4; ++i) aF[i] = *(const bf16x8*)&lds[bb + aRd + i * 512];
#pragma unroll
    for (int n = 0; n < 4; ++n) bF[n] = *(const bf16x8*)&lds[bb + bRd + n * 512];
    if (do_stage) stageA(t + 3);  // buf[(t-1)&3]: all its reads pre-date last BAR
    __builtin_amdgcn_s_barrier();
    asm volatile("s_waitcnt lgkmcnt(0)" ::: "memory");
    __builtin_amdgcn_sched_barrier(0);
    __builtin_amdgcn_s_setprio(1);
#pragma unroll
    for (int m = 0; m < 4; ++m)
#pragma unroll
      for (int n = 0; n < 4; ++n)
        acc[m][n] = __builtin_amdgcn_mfma_f32_16x16x32_bf16(aF[m], bF[n],
                                                            acc[m][n], 0, 0, 0);
    __builtin_amdgcn_s_setprio(0);
    __builtin_amdgcn_sched_barrier(0);
    // ---- phase B: quadrant m4-7 x n0-3 (reads overlap phase-A MFMA drain)
    bf16x8 aH[4];
#pragma unroll
    for (int i = 0; i < 4; ++i)
      aH[i] = *(const bf16x8*)&lds[bb + aRd + (4 + i) * 512];
    if (do_stage) stageB(t + 3);
    if (vm == 8)      asm volatile("s_waitcnt vmcnt(8)" ::: "memory");
    else if (vm == 4) asm volatile("s_waitcnt vmcnt(4)" ::: "memory");
    else if (vm == 0) asm volatile("s_waitcnt vmcnt(0)" ::: "memory");
    __builtin_amdgcn_sched_barrier(0);
    __builtin_amdgcn_s_barrier();  // publishes tile t+1 landed
    asm volatile("s_waitcnt lgkmcnt(0)" ::: "memory");
    __builtin_amdgcn_sched_barrier(0);
    __builtin_amdgcn_s_setprio(1);
#pragma unroll
    for (int m = 0; m < 4; ++m)
#pragma unroll
      for (int n = 0; n < 4; ++n)
        acc[4 + m][n] = __builtin_amdgcn_mfma_f32_16x16x32_bf16(aH[m], bF[n],
                                                                acc[4 + m][n], 0, 0, 0);
    __builtin_amdgcn_s_setprio(0);
    __builtin_amdgcn_sched_barrier(0);
  };

  for (int t = 0; t < NT - 3; ++t) region(t, true, 8);
  region(NT - 3, false, 4);   // outstanding {NT-2, NT-1} -> retire NT-2
  region(NT - 2, false, 0);   // outstanding {NT-1} -> retire NT-1
  region(NT - 1, false, -1);  // all landed

  // C/D layout: col=lane&15, row=(lane>>4)*4+j [m89/m91]
  const int cr = (lane >> 4) * 4;
  const int cc = lane & 15;
#pragma unroll
  for (int m = 0; m < 8; ++m) {
#pragma unroll
    for (int n = 0; n < 4; ++n) {
      float* cp = C + (size_t)(bmRow + wm + m * 16 + cr) * N_DIM +
                  (bnRow + wn + n * 16 + cc);
#pragma unroll
      for (int jj = 0; jj < 4; ++jj) cp[(size_t)jj * N_DIM] = acc[m][n][jj];
    }
  }
}

// ---- fallback chunked GEMM (m97 structure, verified round 2) ----
__global__ __launch_bounds__(256) void gemm_bt_kernel(const __bf16* __restrict__ A,
                                                      const __bf16* __restrict__ B,
                                                      float* __restrict__ C,
                                                      int m0, int n0, int mtiles) {
  __shared__ __align__(16) __bf16 sA[128 * 64];
  __shared__ __align__(16) __bf16 sB[128 * 64];

  const int bid = blockIdx.x;
  const int bm = bid % mtiles;
  const int bn = bid / mtiles;

  const int t = threadIdx.x;
  const int lane = t & 63;
  const int w = t >> 6;
  const int wm = (w >> 1) * 64;
  const int wn = (w & 1) * 64;

  f32x4 acc[4][4] = {};

  const __bf16* gA = A + (size_t)(bm * 128 + (t >> 3)) * K_PAD + (t & 7) * 8;
  const __bf16* gB = B + (size_t)(bn * 128 + (t >> 3)) * K_PAD + (t & 7) * 8;
  char* lA = (char*)sA + t * 16;
  char* lB = (char*)sB + t * 16;

  const int fr = lane & 15;
  const int fo = (lane >> 4) * 8;

  for (int kt = 0; kt < K_PAD / 64; ++kt) {
    const int k0 = kt * 64;
#pragma unroll
    for (int i = 0; i < 4; ++i) {
      async16(gA + k0 + (size_t)i * 32 * K_PAD, lA + i * 4096);
      async16(gB + k0 + (size_t)i * 32 * K_PAD, lB + i * 4096);
    }
    __syncthreads();
#pragma unroll
    for (int kk = 0; kk < 2; ++kk) {
      bf16x8 aF[4], bF[4];
#pragma unroll
      for (int mt = 0; mt < 4; ++mt)
        aF[mt] = *(const bf16x8*)&sA[(wm + mt * 16 + fr) * 64 + kk * 32 + fo];
#pragma unroll
      for (int nt = 0; nt < 4; ++nt)
        bF[nt] = *(const bf16x8*)&sB[(wn + nt * 16 + fr) * 64 + kk * 32 + fo];
#pragma unroll
      for (int mt = 0; mt < 4; ++mt)
#pragma unroll
        for (int nt = 0; nt < 4; ++nt)
          acc[mt][nt] = __builtin_amdgcn_mfma_f32_16x16x32_bf16(
              aF[mt], bF[nt], acc[mt][nt], 0, 0, 0);
    }
    __syncthreads();
  }

  const int cr = (lane >> 4) * 4;
  const int cc = lane & 15;
#pragma unroll
  for (int mt = 0; mt < 4; ++mt) {
#pragma unroll
    for (int nt = 0; nt < 4; ++nt) {
      float* cp = C + (size_t)(m0 + bm * 128 + wm + mt * 16 + cr) * N_DIM +
                  (n0 + bn * 128 + wn + nt * 16 + cc);
#pragma unroll
      for (int j = 0; j < 4; ++j) cp[(size_t)j * N_DIM] = acc[mt][nt][j];
    }
  }
}

// ---- safety net for tiny ws
__global__ __launch_bounds__(256) void naive_kernel(const float* __restrict__ x,
                                                    const float* __restrict__ w,
                                                    const float* __restrict__ arc,
                                                    const int* __restrict__ idx,
                                                    float* __restrict__ out, int no) {
  size_t gid = (size_t)blockIdx.x * 256 + threadIdx.x;
  if (gid >= (size_t)M_DIM * N_DIM) return;
  int m = (int)(gid / N_DIM), o = (int)(gid % N_DIM);
  const float* xr = x + (size_t)m * K_DIM;
  const float* wr = w + (size_t)o * K_DIM;
  float acc = 0.f;
  for (int k = 0; k < K_DIM; ++k) acc += qf(xr[k]) * qf(wr[k]);
  for (int j = 0; j < no; ++j) {
    float xv = xr[idx[j]];
    acc += (xv - qf(xv)) * arc[(size_t)o * no + j];
  }
  out[gid] = acc;
}

extern "C" void kernel_launch(void* const* d_in, const int* in_sizes, int n_in,
                              void* d_out, int out_size, void* d_ws, size_t ws_size,
                              hipStream_t stream) {
  const float* x = (const float*)d_in[0];     // (4,2048,4096)
  const float* wgt = (const float*)d_in[1];   // (4096,4096)
  const float* arc = (const float*)d_in[2];   // (4096,204)
  const int* idx = (const int*)d_in[3];       // (204,)
  float* out = (float*)d_out;                 // (4,2048,4096) fp32
  const int no = in_sizes[3];                 // 204

  const size_t rowb = (size_t)K_PAD * sizeof(__bf16);  // 8704 B per staged row
  const size_t rows_avail = ws_size / rowb;

  if (rows_avail >= (size_t)(N_DIM + M_DIM)) {
    // fast path: full A+B staged, single 256^2 pipelined GEMM
    __bf16* B = (__bf16*)d_ws;
    __bf16* A = B + (size_t)N_DIM * K_PAD;
    prep_w_kernel<<<N_DIM * (K_PAD / 8) / 256, 256, 0, stream>>>(wgt, arc, B, no, 0);
    prep_x_kernel<<<M_DIM * (K_PAD / 8) / 256, 256, 0, stream>>>(x, idx, A, no, 0);
    gemm256_kernel<<<(M_DIM / 256) * (N_DIM / 256), 512, 0, stream>>>(A, B, out);
    return;
  }

  // chunked fallback (multiples of 128 rows)
  size_t nr_c, mr_c;
  if (rows_avail >= (size_t)(N_DIM + 128)) {
    nr_c = N_DIM;
    mr_c = ((rows_avail - N_DIM) / 128) * 128;
    if (mr_c > M_DIM) mr_c = M_DIM;
  } else {
    nr_c = (rows_avail / 2 / 128) * 128;
    if (nr_c > N_DIM) nr_c = N_DIM;
    mr_c = nr_c ? (((rows_avail - nr_c) / 128) * 128) : 0;
    if (mr_c > M_DIM) mr_c = M_DIM;
  }

  if (nr_c == 0 || mr_c == 0) {
    size_t total = (size_t)M_DIM * N_DIM;
    naive_kernel<<<(int)((total + 255) / 256), 256, 0, stream>>>(x, wgt, arc, idx, out, no);
    return;
  }

  __bf16* B = (__bf16*)d_ws;
  __bf16* A = B + nr_c * (size_t)K_PAD;

  for (int n0 = 0; n0 < N_DIM; n0 += (int)nr_c) {
    const int nr = (int)((N_DIM - n0 < (int)nr_c) ? (N_DIM - n0) : (int)nr_c);
    prep_w_kernel<<<nr * (K_PAD / 8) / 256, 256, 0, stream>>>(wgt, arc, B, no, n0);
    for (int m0 = 0; m0 < M_DIM; m0 += (int)mr_c) {
      const int mr = (int)((M_DIM - m0 < (int)mr_c) ? (M_DIM - m0) : (int)mr_c);
      prep_x_kernel<<<mr * (K_PAD / 8) / 256, 256, 0, stream>>>(x, idx, A, no, m0);
      const int mtiles = mr / 128, ntiles = nr / 128;
      gemm_bt_kernel<<<mtiles * ntiles, 256, 0, stream>>>(A, B, out, m0, n0, mtiles);
    }
  }
}